// Round 3
// baseline (2078.510 us; speedup 1.0000x reference)
//
#include <hip/hip_runtime.h>
#include <hip/hip_bf16.h>

#define N 4096
#define D 512
#define NBLK 256      // persistent grid: 256 blocks x 1024 threads (1 block/CU)
#define LA (-8.317766166719343f)            // -log(4096)
#define LAB1 (-16.635532333438686f - 1.0f)  // la + lb + 1

typedef unsigned short u16;
typedef __attribute__((ext_vector_type(8))) short short8;
typedef __attribute__((ext_vector_type(8))) unsigned short ushort8;
typedef __attribute__((ext_vector_type(4))) float fvec4;

static __device__ __forceinline__ float bf2f(unsigned short u) {
    union { unsigned int i; float f; } c;
    c.i = ((unsigned int)u) << 16;
    return c.f;
}

static __device__ __forceinline__ unsigned short f2bf(float x) {
    __hip_bfloat16 h = __float2bfloat16(x);  // RNE
    unsigned short u;
    __builtin_memcpy(&u, &h, 2);
    return u;
}

static __device__ __forceinline__ void gld_lds16(const u16* gp, u16* lp) {
    __builtin_amdgcn_global_load_lds(
        (__attribute__((address_space(1))) void*)(u16*)gp,
        (__attribute__((address_space(3))) void*)lp, 16, 0, 0);
}

// ---------------- fp32 -> bf16 convert (8 elems/thread) ----------------
__global__ __launch_bounds__(256) void f32_to_bf16_k(const float* __restrict__ in,
                                                     u16* __restrict__ out) {
    int idx = blockIdx.x * 256 + threadIdx.x;
    fvec4 a = *((const fvec4*)in + idx * 2);
    fvec4 b = *((const fvec4*)in + idx * 2 + 1);
    ushort8 o;
#pragma unroll
    for (int e = 0; e < 4; ++e) { o[e] = f2bf(a[e]); o[4 + e] = f2bf(b[e]); }
    *((ushort8*)out + idx) = o;
}

// ---------------- row squared-norms: one wave per row ----------------
__global__ __launch_bounds__(256) void row_norms_k(const float* __restrict__ X,
                                                   float* __restrict__ out) {
    int wave = threadIdx.x >> 6;
    int lane = threadIdx.x & 63;
    int row  = blockIdx.x * 4 + wave;
    const float* xr = X + (size_t)row * D;
    float s = 0.f;
#pragma unroll
    for (int k = 0; k < D / 64; ++k) {
        float v = xr[lane + 64 * k];
        s += v * v;
    }
#pragma unroll
    for (int off = 32; off >= 1; off >>= 1) s += __shfl_down(s, off);
    if (lane == 0) out[row] = s;
}

// ---------------- cost matrix via bf16 MFMA (m97 pattern) ----------------
__global__ __launch_bounds__(256) void gemm_cost_bf16_k(const u16* __restrict__ A,
                                                        const u16* __restrict__ B,
                                                        const float* __restrict__ x2,
                                                        const float* __restrict__ y2,
                                                        u16* __restrict__ M) {
    __shared__ u16 As[128 * 32];
    __shared__ u16 Bs[128 * 32];
    int tid = threadIdx.x;
    int wave = tid >> 6, lane = tid & 63;
    int i0 = blockIdx.y * 128, j0 = blockIdx.x * 128;
    int wr = (wave >> 1) * 64, wc = (wave & 1) * 64;

    fvec4 acc[4][4] = {};

    int srow = wave * 16 + (lane >> 2);
    int skk  = (lane & 3) * 8;
    const u16* ga0 = A + (size_t)(i0 + srow) * D + skk;
    const u16* ga1 = A + (size_t)(i0 + 64 + srow) * D + skk;
    const u16* gb0 = B + (size_t)(j0 + srow) * D + skk;
    const u16* gb1 = B + (size_t)(j0 + 64 + srow) * D + skk;
    u16* la0 = &As[(wave * 16) * 32];
    u16* la1 = &As[(64 + wave * 16) * 32];
    u16* lb0 = &Bs[(wave * 16) * 32];
    u16* lb1 = &Bs[(64 + wave * 16) * 32];

    int fr = lane & 15, q = lane >> 4;

    for (int k0 = 0; k0 < D; k0 += 32) {
        __syncthreads();
        gld_lds16(ga0 + k0, la0);
        gld_lds16(ga1 + k0, la1);
        gld_lds16(gb0 + k0, lb0);
        gld_lds16(gb1 + k0, lb1);
        __syncthreads();
        short8 af[4], bf[4];
#pragma unroll
        for (int t = 0; t < 4; ++t) {
            af[t] = *(const short8*)&As[(wr + t * 16 + fr) * 32 + q * 8];
            bf[t] = *(const short8*)&Bs[(wc + t * 16 + fr) * 32 + q * 8];
        }
#pragma unroll
        for (int ri = 0; ri < 4; ++ri)
#pragma unroll
            for (int ci = 0; ci < 4; ++ci)
                acc[ri][ci] = __builtin_amdgcn_mfma_f32_16x16x32_bf16(af[ri], bf[ci],
                                                                      acc[ri][ci], 0, 0, 0);
    }

#pragma unroll
    for (int ri = 0; ri < 4; ++ri) {
#pragma unroll
        for (int ci = 0; ci < 4; ++ci) {
            int j = j0 + wc + ci * 16 + fr;
            float yj = y2[j];
#pragma unroll
            for (int r = 0; r < 4; ++r) {
                int i = i0 + wr + ri * 16 + q * 4 + r;
                float val = fmaxf(x2[i] + yj - 2.0f * acc[ri][ci][r], 0.0f);
                M[(size_t)i * N + j] = f2bf(val);
            }
        }
    }
}

// ---------------- bf16 LDS-tiled transpose ----------------
__global__ __launch_bounds__(256) void transpose_bf16_k(const u16* __restrict__ in,
                                                        u16* __restrict__ out) {
    __shared__ u16 tile[64][66];
    int bx = blockIdx.x * 64, by = blockIdx.y * 64;
    int tx = threadIdx.x & 63, ty = threadIdx.x >> 6;
#pragma unroll
    for (int r = 0; r < 64; r += 4)
        tile[r + ty][tx] = in[(size_t)(by + r + ty) * N + bx + tx];
    __syncthreads();
#pragma unroll
    for (int r = 0; r < 64; r += 4)
        out[(size_t)(bx + r + ty) * N + by + tx] = tile[tx][r + ty];
}

// =====================================================================
// Persistent Sinkhorn v2: 100 iters + value in ONE launch, ZERO fences.
// All cross-XCD traffic via relaxed agent-scope atomics (coherence-point
// ops, no buffer_inv/wbl2 -> M stays L2/L3-resident, unlike round-1).
// 256 blocks x 1024 threads, 16 rows/block (one per wave).
// =====================================================================

static __device__ __forceinline__ int swz(int k) { return k ^ ((k >> 3) & 1); }

static __device__ __forceinline__ float agload(const float* p) {
    return __hip_atomic_load(p, __ATOMIC_RELAXED, __HIP_MEMORY_SCOPE_AGENT);
}
static __device__ __forceinline__ void agstore(float* p, float v) {
    __hip_atomic_store(p, v, __ATOMIC_RELAXED, __HIP_MEMORY_SCOPE_AGENT);
}

// stage 16KB vector (global, written by other XCDs) into LDS, XOR-swizzled.
// Coalesced 4B coherent loads; conflict-free b32 LDS writes.
static __device__ __forceinline__ void stage_vec(const float* __restrict__ vg,
                                                 float* __restrict__ lds) {
    int t = threadIdx.x;
#pragma unroll
    for (int i = 0; i < 4; ++i) {
        int fi = i * 1024 + t;
        float v = agload(vg + fi);
        int k = fi >> 2;
        lds[(swz(k) << 2) | (fi & 3)] = v;
    }
}

// one half-step: vout[row] = logw - LSE_j( vin_lds[j] - R[row][j] )
static __device__ __forceinline__ void half_body(const u16* __restrict__ R,
                                                 const float* __restrict__ lds,
                                                 float* __restrict__ vout, float logw) {
    int wid  = (blockIdx.x << 4) | (threadIdx.x >> 6);  // row 0..4095
    int lane = threadIdx.x & 63;
    const u16* row = R + ((size_t)wid << 12);
    float m = -1e30f, s = 0.f;
#pragma unroll
    for (int c = 0; c < 8; ++c) {
        int j = c * 512 + lane * 8;
        ushort8 m8 = *(const ushort8*)(row + j);
        int k0 = j >> 2;
        fvec4 g0 = *(const fvec4*)&lds[swz(k0) << 2];
        fvec4 g1 = *(const fvec4*)&lds[swz(k0 + 1) << 2];
        const unsigned* mu = (const unsigned*)&m8;
        float tv[8];
#pragma unroll
        for (int k = 0; k < 4; ++k) {
            unsigned u = mu[k];
            float flo = __uint_as_float(u << 16);
            float fhi = __uint_as_float(u & 0xffff0000u);
            float ga = (k < 2) ? g0[2 * k] : g1[2 * k - 4];
            float gb = (k < 2) ? g0[2 * k + 1] : g1[2 * k - 3];
            tv[2 * k]     = ga - flo;
            tv[2 * k + 1] = gb - fhi;
        }
        float mh = tv[0];
#pragma unroll
        for (int e = 1; e < 8; ++e) mh = fmaxf(mh, tv[e]);
        float sh = 0.f;
#pragma unroll
        for (int e = 0; e < 8; ++e) sh += __expf(tv[e] - mh);
        float mn = fmaxf(m, mh);
        s = s * __expf(m - mn) + sh * __expf(mh - mn);
        m = mn;
    }
#pragma unroll
    for (int off = 32; off >= 1; off >>= 1) {
        float mo = __shfl_xor(m, off);
        float so = __shfl_xor(s, off);
        float mn = fmaxf(m, mo);
        s = s * __expf(m - mn) + so * __expf(mo - mn);
        m = mn;
    }
    if (lane == 0) agstore(vout + wid, logw - (m + __logf(s)));
    asm volatile("s_waitcnt vmcnt(0)" ::: "memory");  // store visible pre-barrier
}

// grid barrier: monotonic padded counters, all-blocks-poll, no fences.
static __device__ __forceinline__ void gsync(unsigned* cnt, unsigned round) {
    __syncthreads();  // drains vmcnt for every wave before arrival
    if (threadIdx.x < 32) {
        if (threadIdx.x == 0)
            __hip_atomic_fetch_add(&cnt[(blockIdx.x & 31) << 5], 1u,
                                   __ATOMIC_RELAXED, __HIP_MEMORY_SCOPE_AGENT);
        unsigned target = round * NBLK;
        for (;;) {
            unsigned c = __hip_atomic_load(&cnt[threadIdx.x << 5],
                                           __ATOMIC_RELAXED, __HIP_MEMORY_SCOPE_AGENT);
#pragma unroll
            for (int off = 16; off >= 1; off >>= 1)
                c += (unsigned)__shfl_xor((int)c, off);
            if (c >= target) break;
            __builtin_amdgcn_s_sleep(2);
        }
    }
    __syncthreads();
}

__global__ __launch_bounds__(1024, 4) void sinkhorn_persist2_k(
        const u16* __restrict__ Mb, const u16* __restrict__ MTb,
        float* __restrict__ f, float* __restrict__ g,
        unsigned* cnt, float* __restrict__ partial, float* __restrict__ out) {
    __shared__ float vlds[4096];  // 16 KB staged vector
    __shared__ float ps[16];
    unsigned round = 0;
    for (int it = 0; it < 100; ++it) {
        stage_vec(g, vlds);
        __syncthreads();
        half_body(Mb, vlds, f, LA);
        gsync(cnt, ++round);
        stage_vec(f, vlds);
        __syncthreads();
        half_body(MTb, vlds, g, LA);
        gsync(cnt, ++round);
    }
    // ---- value phase: per-wave partials over Mb rows ----
    stage_vec(g, vlds);
    __syncthreads();
    {
        int wid  = (blockIdx.x << 4) | (threadIdx.x >> 6);
        int lane = threadIdx.x & 63;
        const u16* row = Mb + ((size_t)wid << 12);
        float fi = agload(f + wid);
        float local = 0.f;
#pragma unroll
        for (int c = 0; c < 8; ++c) {
            int j = c * 512 + lane * 8;
            ushort8 m8 = *(const ushort8*)(row + j);
            int k0 = j >> 2;
            fvec4 g0 = *(const fvec4*)&vlds[swz(k0) << 2];
            fvec4 g1 = *(const fvec4*)&vlds[swz(k0 + 1) << 2];
            const unsigned* mu = (const unsigned*)&m8;
#pragma unroll
            for (int k = 0; k < 4; ++k) {
                unsigned u = mu[k];
                float mv0 = __uint_as_float(u << 16);
                float mv1 = __uint_as_float(u & 0xffff0000u);
                float ga = (k < 2) ? g0[2 * k] : g1[2 * k - 4];
                float gb = (k < 2) ? g0[2 * k + 1] : g1[2 * k - 3];
                float a0 = fi + ga, a1 = fi + gb;
                local += __expf(a0 - mv0) * (a0 - LAB1);
                local += __expf(a1 - mv1) * (a1 - LAB1);
            }
        }
#pragma unroll
        for (int off = 32; off >= 1; off >>= 1) local += __shfl_xor(local, off);
        if (lane == 0) ps[threadIdx.x >> 6] = local;
    }
    __syncthreads();
    if (threadIdx.x == 0) {
        float b = 0.f;
#pragma unroll
        for (int w = 0; w < 16; ++w) b += ps[w];
        agstore(partial + blockIdx.x, b);
    }
    asm volatile("s_waitcnt vmcnt(0)" ::: "memory");
    gsync(cnt, ++round);
    if (blockIdx.x == 0) {
        int t = threadIdx.x;
        float s2 = (t < NBLK) ? agload(partial + t) : 0.f;
#pragma unroll
        for (int off = 32; off >= 1; off >>= 1) s2 += __shfl_xor(s2, off);
        __shared__ float fs[16];
        if ((t & 63) == 0) fs[t >> 6] = s2;
        __syncthreads();
        if (t == 0) {
            float tot = 1.0f;
#pragma unroll
            for (int w = 0; w < 16; ++w) tot += fs[w];
            out[0] = tot;
        }
    }
}

// ---------------- fallback path (round-2 verified, 1644 us) ----------------
__global__ __launch_bounds__(256, 4) void sinkhorn_half_w_k(const u16* __restrict__ Mr,
                                                            const float* __restrict__ vin,
                                                            float* __restrict__ vout,
                                                            float logw) {
    int wid  = (blockIdx.x << 2) | (threadIdx.x >> 6);
    int lane = threadIdx.x & 63;
    const u16* row = Mr + ((size_t)wid << 12);
    float m = -1e30f, s = 0.f;
#pragma unroll
    for (int c = 0; c < 8; ++c) {
        int j = c * 512 + lane * 8;
        ushort8 m8 = *(const ushort8*)(row + j);
        fvec4 g0 = *(const fvec4*)(vin + j);
        fvec4 g1 = *(const fvec4*)(vin + j + 4);
        const unsigned* mu = (const unsigned*)&m8;
        float tv[8];
#pragma unroll
        for (int k = 0; k < 4; ++k) {
            unsigned u = mu[k];
            float flo = __uint_as_float(u << 16);
            float fhi = __uint_as_float(u & 0xffff0000u);
            float ga = (k < 2) ? g0[2 * k] : g1[2 * k - 4];
            float gb = (k < 2) ? g0[2 * k + 1] : g1[2 * k - 3];
            tv[2 * k]     = ga - flo;
            tv[2 * k + 1] = gb - fhi;
        }
        float mh = tv[0];
#pragma unroll
        for (int e = 1; e < 8; ++e) mh = fmaxf(mh, tv[e]);
        float sh = 0.f;
#pragma unroll
        for (int e = 0; e < 8; ++e) sh += __expf(tv[e] - mh);
        float mn = fmaxf(m, mh);
        s = s * __expf(m - mn) + sh * __expf(mh - mn);
        m = mn;
    }
#pragma unroll
    for (int off = 32; off >= 1; off >>= 1) {
        float mo = __shfl_xor(m, off);
        float so = __shfl_xor(s, off);
        float mn = fmaxf(m, mo);
        s = s * __expf(m - mn) + so * __expf(mo - mn);
        m = mn;
    }
    if (lane == 0) vout[wid] = logw - (m + __logf(s));
}

__global__ __launch_bounds__(256, 4) void ot_value_w_k(const u16* __restrict__ M,
                                                       const float* __restrict__ f,
                                                       const float* __restrict__ g,
                                                       float* __restrict__ partial) {
    int wid  = (blockIdx.x << 2) | (threadIdx.x >> 6);
    int lane = threadIdx.x & 63;
    const u16* row = M + ((size_t)wid << 12);
    float fi = f[wid];
    float local = 0.f;
#pragma unroll
    for (int c = 0; c < 8; ++c) {
        int j = c * 512 + lane * 8;
        ushort8 m8 = *(const ushort8*)(row + j);
        fvec4 g0 = *(const fvec4*)(g + j);
        fvec4 g1 = *(const fvec4*)(g + j + 4);
        const unsigned* mu = (const unsigned*)&m8;
#pragma unroll
        for (int k = 0; k < 4; ++k) {
            unsigned u = mu[k];
            float mv0 = __uint_as_float(u << 16);
            float mv1 = __uint_as_float(u & 0xffff0000u);
            float ga = (k < 2) ? g0[2 * k] : g1[2 * k - 4];
            float gb = (k < 2) ? g0[2 * k + 1] : g1[2 * k - 3];
            float a0 = fi + ga, a1 = fi + gb;
            local += __expf(a0 - mv0) * (a0 - LAB1);
            local += __expf(a1 - mv1) * (a1 - LAB1);
        }
    }
#pragma unroll
    for (int off = 32; off >= 1; off >>= 1) local += __shfl_xor(local, off);
    __shared__ float ps[4];
    if (lane == 0) ps[threadIdx.x >> 6] = local;
    __syncthreads();
    if (threadIdx.x == 0) partial[blockIdx.x] = ps[0] + ps[1] + ps[2] + ps[3];
}

__global__ __launch_bounds__(256) void value_reduce_k(const float* __restrict__ partial,
                                                      float* __restrict__ out) {
    int t = threadIdx.x;
    float s = partial[t] + partial[t + 256] + partial[t + 512] + partial[t + 768];
#pragma unroll
    for (int off = 32; off >= 1; off >>= 1) s += __shfl_xor(s, off);
    __shared__ float fs[4];
    if ((t & 63) == 0) fs[t >> 6] = s;
    __syncthreads();
    if (t == 0) out[0] = fs[0] + fs[1] + fs[2] + fs[3] + 1.0f;
}

extern "C" void kernel_launch(void* const* d_in, const int* in_sizes, int n_in,
                              void* d_out, int out_size, void* d_ws, size_t ws_size,
                              hipStream_t stream) {
    const float* src = (const float*)d_in[0];
    const float* tgt = (const float*)d_in[1];
    float* out = (float*)d_out;

    // workspace: Mb (32MB) | MTb (32MB) | Xb (4MB) | Yb (4MB) | x2 | y2 | f | g
    // partial + barrier counters alias Xb (dead after the GEMM consumes it).
    u16* Mb  = (u16*)d_ws;
    u16* MTb = Mb + (size_t)N * N;
    u16* Xb  = MTb + (size_t)N * N;
    u16* Yb  = Xb + (size_t)N * D;
    float* x2 = (float*)(Yb + (size_t)N * D);
    float* y2 = x2 + N;
    float* f  = y2 + N;
    float* g  = f + N;

    float* partial = (float*)Xb;                     // NBLK floats
    unsigned* cnt  = (unsigned*)((char*)Xb + 4096);  // 32 x 128B lines (4 KB)

    const float la = -8.317766166719343f;
    const float lb = la;

    hipMemsetAsync(f, 0, 2 * N * sizeof(float), stream);  // f,g contiguous

    f32_to_bf16_k<<<N * D / (256 * 8), 256, 0, stream>>>(src, Xb);
    f32_to_bf16_k<<<N * D / (256 * 8), 256, 0, stream>>>(tgt, Yb);
    row_norms_k<<<N / 4, 256, 0, stream>>>(src, x2);
    row_norms_k<<<N / 4, 256, 0, stream>>>(tgt, y2);
    gemm_cost_bf16_k<<<dim3(N / 128, N / 128), 256, 0, stream>>>(Xb, Yb, x2, y2, Mb);
    transpose_bf16_k<<<dim3(N / 64, N / 64), 256, 0, stream>>>(Mb, MTb);

    hipMemsetAsync(cnt, 0, 4096, stream);  // barrier counters (after gemm used Xb)

    void* kargs[] = {(void*)&Mb, (void*)&MTb, (void*)&f, (void*)&g,
                     (void*)&cnt, (void*)&partial, (void*)&out};
    hipError_t cerr = hipLaunchCooperativeKernel((const void*)sinkhorn_persist2_k,
                                                 dim3(NBLK), dim3(1024), kargs, 0, stream);
    if (cerr != hipSuccess) {
        // fallback: verified 200-launch path (1644 us)
        for (int it = 0; it < 100; ++it) {
            sinkhorn_half_w_k<<<N / 4, 256, 0, stream>>>(Mb,  g, f, la);
            sinkhorn_half_w_k<<<N / 4, 256, 0, stream>>>(MTb, f, g, lb);
        }
        ot_value_w_k<<<N / 4, 256, 0, stream>>>(Mb, f, g, partial);
        value_reduce_k<<<1, 256, 0, stream>>>(partial, out);
    }
}